// Round 8
// baseline (259.883 us; speedup 1.0000x reference)
//
#include <hip/hip_runtime.h>

// ---------------------------------------------------------------------------
// GQA block: out = Attn(x@Wq^T, x@Wk^T, x@Wv^T; sliding-window+sink) @ Wo^T
// B=2 T=2048 C=2048, NH=16 NKV=4 HS=128, WINDOW=1024 SINK=4.
// R15: (a) out-proj REVERTED to R13's gemm_bn128 (R14's sq128 cost +6us:
// halving the tile doubled staging traffic). (b) attn rebuilt as 2 heads x
// 2 key-half waves per block: R13's waves each read the WHOLE K/V tile from
// LDS (4x redundant, ~288KB b128/CU/chunk = LDS-read bound). Now each wave
// computes only its 32-key half of QK^T and PV: kf 8 + vf 8 + pf 2 = 18
// b128/wave/chunk (was 36), MFMA 34 (was 68). kvpack K mapping changed to
// key = nt*16 + l16 (contiguous keys per MFMA) -- P stays P[row][key], PV
// addressing unchanged, each wave reads only the P half it wrote. Heads
// merge O,l via f32 LDS scratch in the epilogue. Grid 1024 (bk=id&7 keeps
// XCD residency), LDS 72KB -> 2 blocks/CU.
// ---------------------------------------------------------------------------

#define T_SEQ 2048
#define NKV   4
#define HS    128
#define CDIM  2048
#define QKVN  3072
#define WIN   1024
#define SINKN 4

typedef __bf16 bf16x8 __attribute__((ext_vector_type(8)));
typedef float  f32x4  __attribute__((ext_vector_type(4)));

#define MFMA16(A, B, C) __builtin_amdgcn_mfma_f32_16x16x32_bf16(A, B, C, 0, 0, 0)
#define EXP2(x) __builtin_amdgcn_exp2f(x)

__device__ inline unsigned short f2bu(float f) {  // fp32 -> bf16 bits, RNE
  unsigned int u = __float_as_uint(f);
  u += 0x7fffu + ((u >> 16) & 1u);
  return (unsigned short)(u >> 16);
}
__device__ inline unsigned short hi16(float f) {  // bf16 truncation
  return (unsigned short)(__float_as_uint(f) >> 16);
}
__device__ inline __bf16 us2b(unsigned short u) {
  union { unsigned short u; __bf16 b; } t; t.u = u; return t.b;
}
__device__ inline f32x4 fzero4() { f32x4 z = {0.f, 0.f, 0.f, 0.f}; return z; }

// async global->LDS, 16B/lane. LDS dest is wave-uniform base + lane*16 (m104).
__device__ __forceinline__ void glds16(const void* g, const void* lds_uniform) {
  typedef __attribute__((address_space(1))) void gv;
  typedef __attribute__((address_space(3))) void lv;
  __builtin_amdgcn_global_load_lds((gv*)(unsigned long long)g,
                                   (lv*)(unsigned int)(unsigned long long)lds_uniform,
                                   16, 0, 0);
}

// ---------------- fused fp32 -> bf16 conversion (all 5 inputs) --------------
#define SZ_X  8388608
#define SZ_WQ 4194304
#define SZ_WK 1048576
#define OFF_WQ (SZ_X)
#define OFF_WK (SZ_X + SZ_WQ)
#define OFF_WV (OFF_WK + SZ_WK)
#define OFF_WO (OFF_WV + SZ_WK)
#define SZ_ALL (OFF_WO + SZ_WQ)

__global__ __launch_bounds__(256) void f2b_all(const float* __restrict__ x,
                                               const float* __restrict__ wq,
                                               const float* __restrict__ wk,
                                               const float* __restrict__ wv,
                                               const float* __restrict__ wo,
                                               unsigned short* __restrict__ out,
                                               float qs) {
  int i = (blockIdx.x * 256 + threadIdx.x) * 4;
  const float* src; int off; float sc = 1.0f;
  if (i < OFF_WQ)      { src = x;  off = 0; }
  else if (i < OFF_WK) { src = wq; off = OFF_WQ; sc = qs; }
  else if (i < OFF_WV) { src = wk; off = OFF_WK; }
  else if (i < OFF_WO) { src = wv; off = OFF_WV; }
  else                 { src = wo; off = OFF_WO; }
  float4 v = *reinterpret_cast<const float4*>(src + (i - off));
  ushort4 o;
  o.x = f2bu(v.x * sc); o.y = f2bu(v.y * sc);
  o.z = f2bu(v.z * sc); o.w = f2bu(v.w * sc);
  *reinterpret_cast<ushort4*>(out + i) = o;
}

__device__ inline void storeC(unsigned short* p, float v) { *p = f2bu(v); }
__device__ inline void storeC(float* p, float v) { *p = v; }

// ---------------- C = A (M,K) @ B^T (N,K), 256x192 2-phase ------------------
// Requires M%256==0, N%192==0, K%64==0, grid=(M/256)*(N/192), grid%8==0.
// LDS: As [buf][kh:2][256][32], Bs [buf][kh:2][192][32]; 64B rows, XOR-bit5
// swizzle (byte ^= row_bit3 << 5). 8 waves as 4Mx2N, per-wave 64x96.
template <typename OutT>
__global__ __launch_bounds__(512, 2) void gemm_bn192(const unsigned short* __restrict__ A,
                                                     const unsigned short* __restrict__ B,
                                                     OutT* __restrict__ C,
                                                     int M, int N, int K) {
  __shared__ __align__(16) unsigned short As[2][16384];  // [buf][2][256][32]
  __shared__ __align__(16) unsigned short Bs[2][12288];  // [buf][2][192][32]
  const int tid  = threadIdx.x;
  const int wave = tid >> 6, lane = tid & 63;
  const int quad = lane >> 4, l16 = lane & 15;
  const int wmi  = wave >> 1, wni = wave & 1;            // 4M x 2N wave grid
  const int sx   = ((l16 >> 3) & 1) << 5;

  const int tmn  = M >> 8;
  const int qq   = gridDim.x >> 3;
  const int swzb = (blockIdx.x & 7) * qq + (blockIdx.x >> 3);
  const int tm   = (swzb % tmn) << 8;
  const int tn   = (swzb / tmn) * 192;

  const int logl = (lane * 16) ^ (((lane >> 5) & 1) << 5);
  const int srow = logl >> 6;           // 0..15
  const int scol = (logl & 63) >> 1;    // 0..31
  const int NT   = K >> 6;

  // A chunk ch in [0,32): kh=ch>>4, rows (ch&15)*16; LDS dst linear ch*1KB.
  auto issueA = [&](int tt, int ch) {
    glds16(&A[(size_t)(tm + (ch & 15) * 16 + srow) * K + (tt << 6) + (ch >> 4) * 32 + scol],
           (const char*)As + ((tt & 1) << 15) + ch * 1024);
  };
  // B chunk (kh, rb): rb in [0,12) -> rows rb*16 of k-half kh; dst linear.
  auto issueB = [&](int tt, int kh, int rb) {
    glds16(&B[(size_t)(tn + rb * 16 + srow) * K + (tt << 6) + kh * 32 + scol],
           (const char*)Bs + (tt & 1) * 24576 + (kh * 12 + rb) * 1024);
  };
  const int g3kh = (wave >= 4) ? 1 : 0;          // G3: waves 0-3 fill kh0
  const int g3rb = (wave >= 4) ? (wave - 4) : (8 + wave);  // rows 128-191 / 0-63

  f32x4 acc[4][6];
#pragma unroll
  for (int i = 0; i < 4; ++i)
#pragma unroll
    for (int j = 0; j < 6; ++j) acc[i][j] = fzero4();

  // prologue: t0 complete (G1+G2+G3 = 7/wave), then t1.G1 (3/wave).
  issueA(0, wave); issueA(0, 8 + wave); issueB(0, 0, wave);            // G1(0)
  issueA(0, 16 + wave); issueA(0, 24 + wave); issueB(0, 1, 4 + wave);  // G2(0)
  issueB(0, g3kh, g3rb);                                               // G3(0)
  if (NT > 1) {
    issueA(1, wave); issueA(1, 8 + wave); issueB(1, 0, wave);          // G1(1)
    asm volatile("s_waitcnt vmcnt(3)" ::: "memory");
  } else {
    asm volatile("s_waitcnt vmcnt(0)" ::: "memory");
  }
  __builtin_amdgcn_s_barrier();

  for (int t = 0; t < NT; ++t) {
    const char* Asc = (const char*)As + ((t & 1) << 15);
    const char* Bsc = (const char*)Bs + (t & 1) * 24576;
    const bool h1 = (t + 1 < NT), h2 = (t + 2 < NT);
    bf16x8 aq[4], bq[6];

    // ---- phase 0: kh0 ----
#pragma unroll
    for (int g = 0; g < 6; ++g)
      bq[g] = *reinterpret_cast<const bf16x8*>(
          Bsc + (((wni * 96 + g * 16 + l16) << 6) + ((quad * 16) ^ sx)));
#pragma unroll
    for (int f = 0; f < 4; ++f)
      aq[f] = *reinterpret_cast<const bf16x8*>(
          Asc + (((wmi * 64 + f * 16 + l16) << 6) + ((quad * 16) ^ sx)));
    if (h1) {  // (t+1).G2 + G3 -> idle buffer (its readers done before tile t)
      issueA(t + 1, 16 + wave); issueA(t + 1, 24 + wave);
      issueB(t + 1, 1, 4 + wave); issueB(t + 1, g3kh, g3rb);
    }
    __builtin_amdgcn_s_barrier();
    asm volatile("s_waitcnt lgkmcnt(0)" ::: "memory");
    __builtin_amdgcn_s_setprio(1);
#pragma unroll
    for (int f = 0; f < 4; ++f)
#pragma unroll
      for (int g = 0; g < 6; ++g) acc[f][g] = MFMA16(aq[f], bq[g], acc[f][g]);
    __builtin_amdgcn_s_setprio(0);
    // need (t).G2+G3 retired (issued ph0 of t-1); keep G1(t+1) + G2G3(t+1).
    if (h1) asm volatile("s_waitcnt vmcnt(7)" ::: "memory");
    else    asm volatile("s_waitcnt vmcnt(0)" ::: "memory");
    __builtin_amdgcn_s_barrier();

    // ---- phase 1: kh1 ----
#pragma unroll
    for (int g = 0; g < 6; ++g)
      bq[g] = *reinterpret_cast<const bf16x8*>(
          Bsc + (12288 + ((wni * 96 + g * 16 + l16) << 6) + ((quad * 16) ^ sx)));
#pragma unroll
    for (int f = 0; f < 4; ++f)
      aq[f] = *reinterpret_cast<const bf16x8*>(
          Asc + (16384 + ((wmi * 64 + f * 16 + l16) << 6) + ((quad * 16) ^ sx)));
    if (h2) {  // (t+2).G1 -> current-buffer kh0 (drained by ph0's lgkm+barrier)
      issueA(t + 2, wave); issueA(t + 2, 8 + wave); issueB(t + 2, 0, wave);
    }
    __builtin_amdgcn_s_barrier();
    asm volatile("s_waitcnt lgkmcnt(0)" ::: "memory");
    __builtin_amdgcn_s_setprio(1);
#pragma unroll
    for (int f = 0; f < 4; ++f)
#pragma unroll
      for (int g = 0; g < 6; ++g) acc[f][g] = MFMA16(aq[f], bq[g], acc[f][g]);
    __builtin_amdgcn_s_setprio(0);
    // need G1(t+1) retired (issued ph1 of t-1); keep G2G3(t+1) + G1(t+2).
    if (h2)      asm volatile("s_waitcnt vmcnt(7)" ::: "memory");
    else if (h1) asm volatile("s_waitcnt vmcnt(4)" ::: "memory");
    else         asm volatile("s_waitcnt vmcnt(0)" ::: "memory");
    __builtin_amdgcn_s_barrier();
  }

  // ---- epilogue ----
#pragma unroll
  for (int fi = 0; fi < 4; ++fi)
#pragma unroll
    for (int g = 0; g < 6; ++g)
#pragma unroll
      for (int r = 0; r < 4; ++r) {
        const int row = tm + wmi * 64 + fi * 16 + quad * 4 + r;
        const int col = tn + wni * 96 + g * 16 + l16;
        storeC(&C[(size_t)row * N + col], acc[fi][g][r]);
      }
}

// ---------------- C = A (M,K) @ B^T (N,K), 256x128 2-phase ------------------
// grid = (M/256)*(N/128); 8 waves as 4Mx2N, per-wave 64x64, BK=64 = 2 k32
// phases. LDS 96KB: As [buf][kh:2][256][32], Bs [buf][kh:2][128][32]; same
// 64B-row + XOR-bit5 swizzle. Pipeline depth 3 chunk-groups, vmcnt(6).
template <typename OutT>
__global__ __launch_bounds__(512, 2) void gemm_bn128(const unsigned short* __restrict__ A,
                                                     const unsigned short* __restrict__ B,
                                                     OutT* __restrict__ C,
                                                     int M, int N, int K) {
  __shared__ __align__(16) unsigned short As[2][16384];  // [buf][2][256][32]
  __shared__ __align__(16) unsigned short Bs[2][8192];   // [buf][2][128][32]
  const int tid  = threadIdx.x;
  const int wave = tid >> 6, lane = tid & 63;
  const int quad = lane >> 4, l16 = lane & 15;
  const int wmi  = wave >> 1, wni = wave & 1;            // 4M x 2N wave grid
  const int sx   = ((l16 >> 3) & 1) << 5;

  const int tmn  = M >> 8;
  const int qq   = gridDim.x >> 3;
  const int swzb = (blockIdx.x & 7) * qq + (blockIdx.x >> 3);
  const int tm   = (swzb % tmn) << 8;
  const int tn   = (swzb / tmn) << 7;

  const int logl = (lane * 16) ^ (((lane >> 5) & 1) << 5);
  const int srow = logl >> 6;           // 0..15
  const int scol = (logl & 63) >> 1;    // 0..31
  const int NT   = K >> 6;

  auto issueA = [&](int tt, int ch) {
    glds16(&A[(size_t)(tm + (ch & 15) * 16 + srow) * K + (tt << 6) + (ch >> 4) * 32 + scol],
           (const char*)As + ((tt & 1) << 15) + ch * 1024);
  };
  auto issueB = [&](int tt, int ch) {
    glds16(&B[(size_t)(tn + (ch & 7) * 16 + srow) * K + (tt << 6) + (ch >> 3) * 32 + scol],
           (const char*)Bs + ((tt & 1) << 14) + ch * 1024);
  };

  f32x4 acc[4][4];
#pragma unroll
  for (int i = 0; i < 4; ++i)
#pragma unroll
    for (int j = 0; j < 4; ++j) acc[i][j] = fzero4();

  // prologue: t0-kh0, t0-kh1, t1-kh0 (3 groups x 3 chunks/wave)
  issueB(0, wave);     issueA(0, wave);      issueA(0, 8 + wave);
  issueB(0, 8 + wave); issueA(0, 16 + wave); issueA(0, 24 + wave);
  if (NT > 1) {
    issueB(1, wave); issueA(1, wave); issueA(1, 8 + wave);
    asm volatile("s_waitcnt vmcnt(6)" ::: "memory");
  } else {
    asm volatile("s_waitcnt vmcnt(3)" ::: "memory");
  }
  __builtin_amdgcn_s_barrier();

  for (int t = 0; t < NT; ++t) {
    const char* Asc = (const char*)As + ((t & 1) << 15);
    const char* Bsc = (const char*)Bs + ((t & 1) << 14);
    const bool h1 = (t + 1 < NT), h2 = (t + 2 < NT);
    bf16x8 aq[4], bq[4];

    // ---- phase 0: kh0 ----
#pragma unroll
    for (int g = 0; g < 4; ++g)
      bq[g] = *reinterpret_cast<const bf16x8*>(
          Bsc + (((wni * 64 + g * 16 + l16) << 6) + ((quad * 16) ^ sx)));
#pragma unroll
    for (int f = 0; f < 4; ++f)
      aq[f] = *reinterpret_cast<const bf16x8*>(
          Asc + (((wmi * 64 + f * 16 + l16) << 6) + ((quad * 16) ^ sx)));
    if (h1) {  // (t+1)-kh1 -> idle buffer
      issueB(t + 1, 8 + wave); issueA(t + 1, 16 + wave); issueA(t + 1, 24 + wave);
    }
    __builtin_amdgcn_s_barrier();
    asm volatile("s_waitcnt lgkmcnt(0)" ::: "memory");
    __builtin_amdgcn_s_setprio(1);
#pragma unroll
    for (int f = 0; f < 4; ++f)
#pragma unroll
      for (int g = 0; g < 4; ++g) acc[f][g] = MFMA16(aq[f], bq[g], acc[f][g]);
    __builtin_amdgcn_s_setprio(0);
    if (h1) asm volatile("s_waitcnt vmcnt(6)" ::: "memory");
    else    asm volatile("s_waitcnt vmcnt(0)" ::: "memory");
    __builtin_amdgcn_s_barrier();

    // ---- phase 1: kh1 ----
#pragma unroll
    for (int g = 0; g < 4; ++g)
      bq[g] = *reinterpret_cast<const bf16x8*>(
          Bsc + (8192 + ((wni * 64 + g * 16 + l16) << 6) + ((quad * 16) ^ sx)));
#pragma unroll
    for (int f = 0; f < 4; ++f)
      aq[f] = *reinterpret_cast<const bf16x8*>(
          Asc + (16384 + ((wmi * 64 + f * 16 + l16) << 6) + ((quad * 16) ^ sx)));
    if (h2) {  // (t+2)-kh0 -> current buffer; reads retired at ph0 barrier.
      issueB(t + 2, wave); issueA(t + 2, wave); issueA(t + 2, 8 + wave);
    }
    __builtin_amdgcn_s_barrier();
    asm volatile("s_waitcnt lgkmcnt(0)" ::: "memory");
    __builtin_amdgcn_s_setprio(1);
#pragma unroll
    for (int f = 0; f < 4; ++f)
#pragma unroll
      for (int g = 0; g < 4; ++g) acc[f][g] = MFMA16(aq[f], bq[g], acc[f][g]);
    __builtin_amdgcn_s_setprio(0);
    if (h2)      asm volatile("s_waitcnt vmcnt(6)" ::: "memory");
    else if (h1) asm volatile("s_waitcnt vmcnt(3)" ::: "memory");
    else         asm volatile("s_waitcnt vmcnt(0)" ::: "memory");
    __builtin_amdgcn_s_barrier();
  }

  // ---- epilogue ----
#pragma unroll
  for (int fi = 0; fi < 4; ++fi)
#pragma unroll
    for (int g = 0; g < 4; ++g)
#pragma unroll
      for (int r = 0; r < 4; ++r) {
        const int row = tm + wmi * 64 + fi * 16 + quad * 4 + r;
        const int col = tn + wni * 64 + g * 16 + l16;
        storeC(&C[(size_t)row * N + col], acc[fi][g][r]);
      }
}

// ---------------- K/V fragment packing --------------------------------------
// Kp: per (bk, kt64) an 8192-elem block; tile (c,nt) holds lane-linear
//     B-fragments with CONTIGUOUS keys per nt: elem(lane=quad*16+l16, j) =
//     K[key = nt*16 + l16][c*32 + quad*8 + j]  (R15: was l16*4+nt)
// Vp: per (bk, kt32) a 4096-elem block; tile dt: elem(lane,j) =
//     V[key=kt+quad*8+j][dim=dt*16+l16]
__global__ __launch_bounds__(256) void kvpack(const unsigned short* __restrict__ QKV,
                                              unsigned short* __restrict__ Kp,
                                              unsigned short* __restrict__ Vp) {
  const int tid  = threadIdx.x;
  const int kt64 = blockIdx.x;           // 0..31
  const int bk   = blockIdx.y;           // b*4 + kvh
  const int b = bk >> 2, kvh = bk & 3;
  const int kt = kt64 * 64;
  const int bT = b * T_SEQ;
  const int dq = tid & 15;               // dim octet: dims dq*8..dq*8+7

  unsigned short* kdst = &Kp[(size_t)(bk * 32 + kt64) * 8192];
#pragma unroll
  for (int it = 0; it < 4; ++it) {
    int key = it * 16 + (tid >> 4);
    float4 v = *reinterpret_cast<const float4*>(
        &QKV[(size_t)(bT + kt + key) * QKVN + 2048 + kvh * HS + dq * 8]);
    int c = dq >> 2, quad = dq & 3, nt = key >> 4, l16s = key & 15;
    *reinterpret_cast<float4*>(
        &kdst[((size_t)((c * 4 + nt) * 64 + quad * 16 + l16s)) * 8]) = v;
  }

#pragma unroll
  for (int it = 0; it < 4; ++it) {
    int key = it * 16 + (tid >> 4);
    float4 v = *reinterpret_cast<const float4*>(
        &QKV[(size_t)(bT + kt + key) * QKVN + 2560 + kvh * HS + dq * 8]);
    const unsigned short* pv = reinterpret_cast<const unsigned short*>(&v);
    int kt32 = kt64 * 2 + (key >> 5);
    int quad = (key & 31) >> 3, j = key & 7;
    unsigned short* vdst = &Vp[(size_t)(bk * 64 + kt32) * 4096];
#pragma unroll
    for (int j2 = 0; j2 < 8; ++j2) {
      int d = dq * 8 + j2, dt = d >> 4, l16v = d & 15;
      vdst[((size_t)(dt * 64 + quad * 16 + l16v)) * 8 + j] = pv[j2];
    }
  }
}

// ---------------- flash attention, 2 heads x 2 key-half waves ---------------
// grid 1024 = 8 bk x 2 head-pairs x 64 q-tiles; bk = blockIdx.x & 7 keeps
// each KV group's q-tiles on one XCD (K/V L2-resident). Block 256 = 4 waves:
// wave w -> head hh = w>>1 of the pair, key-half kcw = w&1 of each 64-key
// chunk. Each wave: QK^T over its 32 keys (nt = 2*kcw+ntp, contiguous keys
// via the R15 kvpack layout), P written/read wave-locally (shared per-head
// P[32][64], disjoint halves even under the XOR swizzle -- bijective), PV
// over its V half. O,l merged across the wave pair in the epilogue via f32
// LDS scratch. K/V double-buffered with counted vmcnt(8) as in R13.
__global__ __launch_bounds__(256) void attn_kernel(const unsigned short* __restrict__ QKV,
                                                   const unsigned short* __restrict__ Kp,
                                                   const unsigned short* __restrict__ Vp,
                                                   unsigned short* __restrict__ Y) {
  __shared__ __align__(16) unsigned short Ks[2][8192];
  __shared__ __align__(16) unsigned short Vs[2][8192];
  __shared__ __align__(16) unsigned short Ps[2][2048];   // [head][32][64]

  const int tid  = threadIdx.x;
  const int wave = tid >> 6, lane = tid & 63;
  const int quad = lane >> 4, l16 = lane & 15;
  const int hh   = wave >> 1, kcw = wave & 1;
  const int bk   = blockIdx.x & 7;                        // XCD-resident group
  const int idx2 = blockIdx.x >> 3;                       // 0..127
  const int hp   = idx2 & 1;                              // head pair in group
  const int seq  = idx2 >> 1;                             // 0..63
  const int qt0  = (63 - seq) * 32;                       // long blocks first
  const int kvh  = bk & 3, b = bk >> 2;
  const int h    = kvh * 4 + hp * 2 + hh;
  const int bT   = b * T_SEQ;
  char* Pw = (char*)&Ps[hh][0];

  // Q fragments (A-operand: m=l16, k=quad*8+j); Q pre-scaled by log2e/sqrt(HS)
  bf16x8 qa[2][4];
#pragma unroll
  for (int mt = 0; mt < 2; ++mt)
#pragma unroll
    for (int c = 0; c < 4; ++c)
      qa[mt][c] = *reinterpret_cast<const bf16x8*>(
          &QKV[(size_t)(bT + qt0 + mt * 16 + l16) * QKVN + h * HS + c * 32 + quad * 8]);

  bf16x8 ones;
#pragma unroll
  for (int j = 0; j < 8; ++j) ones[j] = us2b(0x3F80);  // bf16 1.0

  f32x4 o[2][9];   // [mt][dt]; dt=8 accumulates this wave's partial row-sum l
#pragma unroll
  for (int mt = 0; mt < 2; ++mt)
#pragma unroll
    for (int dt = 0; dt < 9; ++dt) o[mt][dt] = fzero4();

  const int start = (qt0 >= 1024) ? ((qt0 - 1023) & ~63) : 0;
  const int sink  = (start > 0) ? 1 : 0;
  const int nch   = ((qt0 + 32 - start + 63) >> 6) + sink;

  // stage chunk ci into buffer buf (8 glds16/wave: 4 K parts + 4 V parts)
  auto stage = [&](int ci, int buf) {
    const int kt = (sink && ci == 0) ? 0 : start + (ci - sink) * 64;
    const unsigned short* kg = &Kp[(size_t)(bk * 32 + (kt >> 6)) * 8192 + lane * 8];
    const unsigned short* vg = &Vp[(size_t)(bk * 64 + (kt >> 5)) * 4096 + lane * 8];
#pragma unroll
    for (int i = 0; i < 4; ++i) {
      int part = wave * 4 + i;                    // wave-uniform
      glds16(kg + part * 512, &Ks[buf][part * 512]);
      glds16(vg + part * 512, &Vs[buf][part * 512]);
    }
  };

  stage(0, 0);

  for (int ci = 0; ci < nch; ++ci) {
    const int  buf = ci & 1;
    const bool is_sink = (sink && ci == 0);
    const int  kt  = is_sink ? 0 : start + (ci - sink) * 64;
    const int  rem = qt0 + 32 - kt;
    const int  kcmax = is_sink ? 1 : (rem >= 64 ? 2 : ((rem + 31) >> 5));
    const bool full  = !is_sink && (kt + 63 <= qt0) && (kt >= qt0 - 992);

    if (ci + 1 < nch) {
      stage(ci + 1, buf ^ 1);     // idle buffer; its readers finished >=1
                                  // barrier ago (end of iteration ci-1)
      asm volatile("s_waitcnt vmcnt(8)" ::: "memory");   // cur chunk landed
    } else {
      asm volatile("s_waitcnt vmcnt(0)" ::: "memory");
    }
    __builtin_amdgcn_s_barrier();

    // wave kcw handles keys [kcw*32, kcw*32+32). When kcmax==1, kcw=1's keys
    // are provably all masked (rem<=32 or sink) -> skip all compute.
    if (kcw < kcmax) {
      // ---- S = Q K^T over this wave's 2 nt tiles (contiguous keys) ----
      f32x4 s[2][2];
      s[0][0] = fzero4(); s[0][1] = fzero4();
      s[1][0] = fzero4(); s[1][1] = fzero4();
      __builtin_amdgcn_s_setprio(1);
#pragma unroll
      for (int c = 0; c < 4; ++c) {
#pragma unroll
        for (int ntp = 0; ntp < 2; ++ntp) {
          bf16x8 kf = *reinterpret_cast<const bf16x8*>(
              &Ks[buf][(c * 4 + 2 * kcw + ntp) * 512 + lane * 8]);
          s[0][ntp] = MFMA16(qa[0][c], kf, s[0][ntp]);
          s[1][ntp] = MFMA16(qa[1][c], kf, s[1][ntp]);
        }
      }
      __builtin_amdgcn_s_setprio(0);

      // ---- P = exp2(S), key of (ntp, l16) = kt + (2*kcw+ntp)*16 + l16 ----
      if (full) {
#pragma unroll
        for (int mt = 0; mt < 2; ++mt)
#pragma unroll
          for (int r = 0; r < 4; ++r) {
            const int row = mt * 16 + quad * 4 + r;
            const int swz = (row & 7) << 4;
#pragma unroll
            for (int ntp = 0; ntp < 2; ++ntp) {
              int e2 = (2 * kcw + ntp) * 32 + l16 * 2;   // byte offset in row
              *reinterpret_cast<unsigned short*>(Pw + ((row * 128 + e2) ^ swz)) =
                  hi16(EXP2(s[mt][ntp][r]));
            }
          }
      } else {
#pragma unroll
        for (int mt = 0; mt < 2; ++mt)
#pragma unroll
          for (int r = 0; r < 4; ++r) {
            const int row = mt * 16 + quad * 4 + r;
            const int qi  = qt0 + row;
            const int swz = (row & 7) << 4;
#pragma unroll
            for (int ntp = 0; ntp < 2; ++ntp) {
              int kj = kt + (2 * kcw + ntp) * 16 + l16;
              bool ok = ((kj <= qi) && (kj + (WIN - 1) >= qi)) ||
                        ((kj < SINKN) && (qi >= SINKN));
              float p = ok ? EXP2(s[mt][ntp][r]) : 0.f;
              int e2 = (2 * kcw + ntp) * 32 + l16 * 2;
              *reinterpret_cast<unsigned short*>(Pw + ((row * 128 + e2) ^ swz)) =
                  hi16(p);
            }
          }
      }
      asm volatile("s_waitcnt lgkmcnt(0)" ::: "memory");  // wave-local P drain

      // ---- O += P V over this wave's V half (kc = kcw) ----
      __builtin_amdgcn_s_setprio(1);
      bf16x8 pf[2];
#pragma unroll
      for (int mt = 0; mt < 2; ++mt) {
        const int prow = mt * 16 + l16;
        pf[mt] = *reinterpret_cast<const bf16x8*>(
            Pw + ((prow * 128 + kcw * 64 + quad * 16) ^ ((prow & 7) << 4)));
      }
#pragma unroll
      for (int dt = 0; dt < 8; ++dt) {
        bf16x8 vf = *reinterpret_cast<const bf16x8*>(
            &Vs[buf][kcw * 4096 + dt * 512 + lane * 8]);
        o[0][dt] = MFMA16(pf[0], vf, o[0][dt]);
        o[1][dt] = MFMA16(pf[1], vf, o[1][dt]);
      }
      o[0][8] = MFMA16(pf[0], ones, o[0][8]);
      o[1][8] = MFMA16(pf[1], ones, o[1][8]);
      __builtin_amdgcn_s_setprio(0);
    }
    asm volatile("" ::: "memory");
    __builtin_amdgcn_s_barrier();   // all reads of buf done -> restage-safe
  }

  // ---- merge wave pair (O, l), normalize, coalesced Y store ----
  __syncthreads();                       // full drain before buffer reuse
  // scratch: head hh region = Ks (hh=0) or Vs (hh=1); o-dump in [0, 18432),
  // Yst (32x128 bf16) at [20480, 28672).
  {
    char* scr = (hh == 0) ? (char*)&Ks[0][0] : (char*)&Vs[0][0];
    if (kcw == 1) {
#pragma unroll
      for (int mt = 0; mt < 2; ++mt)
#pragma unroll
        for (int dt = 0; dt < 9; ++dt)
          *reinterpret_cast<f32x4*>(scr + ((mt * 9 + dt) * 64 + lane) * 16) =
              o[mt][dt];
    }
    __syncthreads();
    if (kcw == 0) {
      char* yst = scr + 20480;
#pragma unroll
      for (int mt = 0; mt < 2; ++mt) {
#pragma unroll
        for (int dt = 0; dt < 9; ++dt) {
          f32x4 part = *reinterpret_cast<const f32x4*>(
              scr + ((mt * 9 + dt) * 64 + lane) * 16);
#pragma unroll
          for (int r = 0; r < 4; ++r) o[mt][dt][r] += part[r];
        }
        float inv[4];
#pragma unroll
        for (int r = 0; r < 4; ++r) inv[r] = __builtin_amdgcn_rcpf(o[mt][8][r]);
#pragma unroll
        for (int dt = 0; dt < 8; ++dt)
#pragma unroll
          for (int r = 0; r < 4; ++r)
            *reinterpret_cast<unsigned short*>(
                yst + ((mt * 16 + quad * 4 + r) * 128 + dt * 16 + l16) * 2) =
                f2bu(o[mt][dt][r] * inv[r]);
      }
    }
  }
  __syncthreads();
#pragma unroll
  for (int it = 0; it < 4; ++it) {
    int idx = it * 256 + tid;            // 0..1023 = 2 heads x 512 uint4
    int hh2 = idx >> 9, rem2 = idx & 511;
    int row = rem2 >> 4, colc = (rem2 & 15) * 8;
    const char* src = ((hh2 == 0) ? (const char*)&Ks[0][0] : (const char*)&Vs[0][0]) +
                      20480 + (row * 128 + colc) * 2;
    *reinterpret_cast<uint4*>(
        &Y[(size_t)(bT + qt0 + row) * CDIM + kvh * 512 + hp * 256 + hh2 * 128 + colc]) =
        *reinterpret_cast<const uint4*>(src);
  }
}

// ---------------------------------------------------------------------------
extern "C" void kernel_launch(void* const* d_in, const int* in_sizes, int n_in,
                              void* d_out, int out_size, void* d_ws, size_t ws_size,
                              hipStream_t stream) {
  const float* x  = (const float*)d_in[0];
  const float* Wq = (const float*)d_in[1];
  const float* Wk = (const float*)d_in[2];
  const float* Wv = (const float*)d_in[3];
  const float* Wo = (const float*)d_in[4];
  float* out = (float*)d_out;

  // workspace layout (bf16 elems); total 62.9 MB
  unsigned short* base = (unsigned short*)d_ws;
  unsigned short* xb   = base;              // x bf16 (8388608); later Y
  unsigned short* wqb  = xb + OFF_WQ;       // Wq bf16; later Kp+Vp
  unsigned short* wob  = xb + OFF_WO;       // Wo bf16
  unsigned short* QKVb = xb + SZ_ALL;       // QKV (4096 x 3072)
  unsigned short* Kpb  = wqb;               // packed K (2097152)
  unsigned short* Vpb  = wqb + 2097152;     // packed V (2097152)
  unsigned short* Yb   = xb;                // attn out (4096 x 2048)

  // 1/sqrt(HS) * log2(e) folded into Wq so exp2 is native
  const float qscale = 0.08838834764831845f * 1.4426950408889634f;
  f2b_all<<<SZ_ALL / 1024, 256, 0, stream>>>(x, Wq, Wk, Wv, Wo, xb, qscale);

  // fused QKV projection: 256x192 tiles -> 16x16 = 256 blocks (full GPU)
  gemm_bn192<unsigned short><<<256, 512, 0, stream>>>(xb, wqb, QKVb, 4096, QKVN, 2048);

  kvpack<<<dim3(32, 8), 256, 0, stream>>>(QKVb, Kpb, Vpb);

  // attention: 1D grid 1024, bk = id&7 -> per-XCD K/V residency
  attn_kernel<<<1024, 256, 0, stream>>>(QKVb, Kpb, Vpb, Yb);

  // output projection: 256x128 tiles -> 16x16 = 256 blocks (R13 config)
  gemm_bn128<float><<<256, 512, 0, stream>>>(Yb, wob, out, 4096, 2048, 2048);
}

// Round 9
// 252.204 us; speedup vs baseline: 1.0304x; 1.0304x over previous
//
#include <hip/hip_runtime.h>

// ---------------------------------------------------------------------------
// GQA block: out = Attn(x@Wq^T, x@Wk^T, x@Wv^T; sliding-window+sink) @ Wo^T
// B=2 T=2048 C=2048, NH=16 NKV=4 HS=128, WINDOW=1024 SINK=4.
// R16: (a) attn + kvpack reverted to exact R13 (best known total 249.0us;
// R15's head/key-half split doubled staging and regressed +11us). (b) GEMMs
// de-serialized: removed the forced s_waitcnt lgkmcnt(0) before each MFMA
// burst (compiler emits fine-grained partial lgkm waits, m97-style, letting
// early MFMAs overlap remaining ds_reads) and removed the opening barrier of
// each phase (all glds-vs-read hazards are gated by the closing barrier +
// MFMA consumption + vmcnt ledger; 4 -> 2 barriers per K-tile, inter-wave
// skew now overlaps reads with MFMA). (c) bn192 latent race fixed: G3's
// B-chunks (kh0 rows 128-191 / kh1 rows 0-63) moved from the ph0-issued
// G2-group into the ph1-issued G1-group so their vmcnt drain (end of ph1,
// vmcnt(7)) precedes their ph0 use. New groups: G1 = {A kh0 x2, B(0,wave),
// G3} (4 loads, issued ph1 for t+2), G2 = {A kh1 x2, B(1,4+wave)} (3 loads,
// issued ph0 for t+1). Ledger: prologue vmcnt(4); steady vmcnt(7)/vmcnt(7);
// tails 3 -> 0.
// ---------------------------------------------------------------------------

#define T_SEQ 2048
#define NKV   4
#define HS    128
#define CDIM  2048
#define QKVN  3072
#define WIN   1024
#define SINKN 4

typedef __bf16 bf16x8 __attribute__((ext_vector_type(8)));
typedef float  f32x4  __attribute__((ext_vector_type(4)));

#define MFMA16(A, B, C) __builtin_amdgcn_mfma_f32_16x16x32_bf16(A, B, C, 0, 0, 0)
#define EXP2(x) __builtin_amdgcn_exp2f(x)

__device__ inline unsigned short f2bu(float f) {  // fp32 -> bf16 bits, RNE
  unsigned int u = __float_as_uint(f);
  u += 0x7fffu + ((u >> 16) & 1u);
  return (unsigned short)(u >> 16);
}
// pack hi16(f0), hi16(f1) -> one u32 (bf16 truncation; bias cancels in O/l)
__device__ inline unsigned int pkhi(float f0, float f1) {
  return __builtin_amdgcn_perm(__float_as_uint(f1), __float_as_uint(f0),
                               0x07060302u);
}
__device__ inline __bf16 us2b(unsigned short u) {
  union { unsigned short u; __bf16 b; } t; t.u = u; return t.b;
}
__device__ inline f32x4 fzero4() { f32x4 z = {0.f, 0.f, 0.f, 0.f}; return z; }

// async global->LDS, 16B/lane. LDS dest is wave-uniform base + lane*16 (m104).
__device__ __forceinline__ void glds16(const void* g, const void* lds_uniform) {
  typedef __attribute__((address_space(1))) void gv;
  typedef __attribute__((address_space(3))) void lv;
  __builtin_amdgcn_global_load_lds((gv*)(unsigned long long)g,
                                   (lv*)(unsigned int)(unsigned long long)lds_uniform,
                                   16, 0, 0);
}

// ---------------- fused fp32 -> bf16 conversion (all 5 inputs) --------------
#define SZ_X  8388608
#define SZ_WQ 4194304
#define SZ_WK 1048576
#define OFF_WQ (SZ_X)
#define OFF_WK (SZ_X + SZ_WQ)
#define OFF_WV (OFF_WK + SZ_WK)
#define OFF_WO (OFF_WV + SZ_WK)
#define SZ_ALL (OFF_WO + SZ_WQ)

__global__ __launch_bounds__(256) void f2b_all(const float* __restrict__ x,
                                               const float* __restrict__ wq,
                                               const float* __restrict__ wk,
                                               const float* __restrict__ wv,
                                               const float* __restrict__ wo,
                                               unsigned short* __restrict__ out,
                                               float qs) {
  int i = (blockIdx.x * 256 + threadIdx.x) * 4;
  const float* src; int off; float sc = 1.0f;
  if (i < OFF_WQ)      { src = x;  off = 0; }
  else if (i < OFF_WK) { src = wq; off = OFF_WQ; sc = qs; }
  else if (i < OFF_WV) { src = wk; off = OFF_WK; }
  else if (i < OFF_WO) { src = wv; off = OFF_WV; }
  else                 { src = wo; off = OFF_WO; }
  float4 v = *reinterpret_cast<const float4*>(src + (i - off));
  ushort4 o;
  o.x = f2bu(v.x * sc); o.y = f2bu(v.y * sc);
  o.z = f2bu(v.z * sc); o.w = f2bu(v.w * sc);
  *reinterpret_cast<ushort4*>(out + i) = o;
}

__device__ inline void storeC(unsigned short* p, float v) { *p = f2bu(v); }
__device__ inline void storeC(float* p, float v) { *p = v; }

// ---------------- C = A (M,K) @ B^T (N,K), 256x192 2-phase ------------------
// Requires M%256==0, N%192==0, K%64==0, grid=(M/256)*(N/192), grid%8==0.
// LDS: As [buf][kh:2][256][32], Bs [buf][kh:2][192][32]; 64B rows, XOR-bit5
// swizzle (byte ^= row_bit3 << 5). 8 waves as 4Mx2N, per-wave 64x96.
// Groups per wave: G1 (ph1-issued, for t+2) = {A ch wave, A ch 8+wave,
// B(0,wave), G3}; G2 (ph0-issued, for t+1) = {A ch 16+wave, A ch 24+wave,
// B(1,4+wave)}. G3: waves 0-3 -> B(0, 8+wave) [kh0 rows 128-191]; waves 4-7
// -> B(1, wave-4) [kh1 rows 0-63].
template <typename OutT>
__global__ __launch_bounds__(512, 2) void gemm_bn192(const unsigned short* __restrict__ A,
                                                     const unsigned short* __restrict__ B,
                                                     OutT* __restrict__ C,
                                                     int M, int N, int K) {
  __shared__ __align__(16) unsigned short As[2][16384];  // [buf][2][256][32]
  __shared__ __align__(16) unsigned short Bs[2][12288];  // [buf][2][192][32]
  const int tid  = threadIdx.x;
  const int wave = tid >> 6, lane = tid & 63;
  const int quad = lane >> 4, l16 = lane & 15;
  const int wmi  = wave >> 1, wni = wave & 1;            // 4M x 2N wave grid
  const int sx   = ((l16 >> 3) & 1) << 5;

  const int tmn  = M >> 8;
  const int qq   = gridDim.x >> 3;
  const int swzb = (blockIdx.x & 7) * qq + (blockIdx.x >> 3);
  const int tm   = (swzb % tmn) << 8;
  const int tn   = (swzb / tmn) * 192;

  const int logl = (lane * 16) ^ (((lane >> 5) & 1) << 5);
  const int srow = logl >> 6;           // 0..15
  const int scol = (logl & 63) >> 1;    // 0..31
  const int NT   = K >> 6;

  // A chunk ch in [0,32): kh=ch>>4, rows (ch&15)*16; LDS dst linear ch*1KB.
  auto issueA = [&](int tt, int ch) {
    glds16(&A[(size_t)(tm + (ch & 15) * 16 + srow) * K + (tt << 6) + (ch >> 4) * 32 + scol],
           (const char*)As + ((tt & 1) << 15) + ch * 1024);
  };
  // B chunk (kh, rb): rb in [0,12) -> rows rb*16 of k-half kh; dst linear.
  auto issueB = [&](int tt, int kh, int rb) {
    glds16(&B[(size_t)(tn + rb * 16 + srow) * K + (tt << 6) + kh * 32 + scol],
           (const char*)Bs + (tt & 1) * 24576 + (kh * 12 + rb) * 1024);
  };
  const int g3kh = (wave >= 4) ? 1 : 0;
  const int g3rb = (wave >= 4) ? (wave - 4) : (8 + wave);

  auto issueG1 = [&](int tt) {   // 4 loads: kh0 A + kh0 B rows 0-127 + G3
    issueA(tt, wave); issueA(tt, 8 + wave);
    issueB(tt, 0, wave); issueB(tt, g3kh, g3rb);
  };
  auto issueG2 = [&](int tt) {   // 3 loads: kh1 A + kh1 B rows 64-191
    issueA(tt, 16 + wave); issueA(tt, 24 + wave); issueB(tt, 1, 4 + wave);
  };

  f32x4 acc[4][6];
#pragma unroll
  for (int i = 0; i < 4; ++i)
#pragma unroll
    for (int j = 0; j < 6; ++j) acc[i][j] = fzero4();

  // prologue: t0 complete (G1+G2 = 7/wave), then t1.G1 (4/wave); drain t0.
  issueG1(0); issueG2(0);
  if (NT > 1) {
    issueG1(1);
    asm volatile("s_waitcnt vmcnt(4)" ::: "memory");
  } else {
    asm volatile("s_waitcnt vmcnt(0)" ::: "memory");
  }
  __builtin_amdgcn_s_barrier();

  for (int t = 0; t < NT; ++t) {
    const char* Asc = (const char*)As + ((t & 1) << 15);
    const char* Bsc = (const char*)Bs + (t & 1) * 24576;
    const bool h1 = (t + 1 < NT), h2 = (t + 2 < NT);
    bf16x8 aq[4], bq[6];

    // ---- phase 0: kh0 (G1(t) confirmed at end of ph1(t-1) / prologue) ----
#pragma unroll
    for (int g = 0; g < 6; ++g)
      bq[g] = *reinterpret_cast<const bf16x8*>(
          Bsc + (((wni * 96 + g * 16 + l16) << 6) + ((quad * 16) ^ sx)));
#pragma unroll
    for (int f = 0; f < 4; ++f)
      aq[f] = *reinterpret_cast<const bf16x8*>(
          Asc + (((wmi * 64 + f * 16 + l16) << 6) + ((quad * 16) ^ sx)));
    if (h1) issueG2(t + 1);   // idle buffer; its readers done >=1 barrier ago
    __builtin_amdgcn_s_setprio(1);
#pragma unroll
    for (int f = 0; f < 4; ++f)
#pragma unroll
      for (int g = 0; g < 6; ++g) acc[f][g] = MFMA16(aq[f], bq[g], acc[f][g]);
    __builtin_amdgcn_s_setprio(0);
    // drain G2(t) (issued ph0(t-1)) before ph1 reads kh1; keep G1(t+1)[4] +
    // G2(t+1)[3] = 7.
    if (h1) asm volatile("s_waitcnt vmcnt(7)" ::: "memory");
    else    asm volatile("s_waitcnt vmcnt(0)" ::: "memory");
    __builtin_amdgcn_s_barrier();

    // ---- phase 1: kh1 ----
#pragma unroll
    for (int g = 0; g < 6; ++g)
      bq[g] = *reinterpret_cast<const bf16x8*>(
          Bsc + (12288 + ((wni * 96 + g * 16 + l16) << 6) + ((quad * 16) ^ sx)));
#pragma unroll
    for (int f = 0; f < 4; ++f)
      aq[f] = *reinterpret_cast<const bf16x8*>(
          Asc + (16384 + ((wmi * 64 + f * 16 + l16) << 6) + ((quad * 16) ^ sx)));
    // G1(t+2) -> current-buffer kh0: its reads were consumed before ph0's
    // closing barrier, which precedes this issue.
    if (h2) issueG1(t + 2);
    __builtin_amdgcn_s_setprio(1);
#pragma unroll
    for (int f = 0; f < 4; ++f)
#pragma unroll
      for (int g = 0; g < 6; ++g) acc[f][g] = MFMA16(aq[f], bq[g], acc[f][g]);
    __builtin_amdgcn_s_setprio(0);
    // drain G1(t+1) (issued ph1(t-1)) before next ph0; keep G2(t+1)[3] +
    // G1(t+2)[4] = 7.
    if (h2)      asm volatile("s_waitcnt vmcnt(7)" ::: "memory");
    else if (h1) asm volatile("s_waitcnt vmcnt(3)" ::: "memory");
    else         asm volatile("s_waitcnt vmcnt(0)" ::: "memory");
    __builtin_amdgcn_s_barrier();
  }

  // ---- epilogue ----
#pragma unroll
  for (int fi = 0; fi < 4; ++fi)
#pragma unroll
    for (int g = 0; g < 6; ++g)
#pragma unroll
      for (int r = 0; r < 4; ++r) {
        const int row = tm + wmi * 64 + fi * 16 + quad * 4 + r;
        const int col = tn + wni * 96 + g * 16 + l16;
        storeC(&C[(size_t)row * N + col], acc[fi][g][r]);
      }
}

// ---------------- C = A (M,K) @ B^T (N,K), 256x128 2-phase ------------------
// grid = (M/256)*(N/128); 8 waves as 4Mx2N, per-wave 64x64, BK=64 = 2 k32
// phases. LDS 96KB; same 64B-row + XOR-bit5 swizzle. Groups per wave:
// kh0 = {B w, A w, A 8+w} (ph1-issued for t+2), kh1 = {B 8+w, A 16+w,
// A 24+w} (ph0-issued for t+1). Ledger: steady vmcnt(6)/6, tails 3->0.
template <typename OutT>
__global__ __launch_bounds__(512, 2) void gemm_bn128(const unsigned short* __restrict__ A,
                                                     const unsigned short* __restrict__ B,
                                                     OutT* __restrict__ C,
                                                     int M, int N, int K) {
  __shared__ __align__(16) unsigned short As[2][16384];  // [buf][2][256][32]
  __shared__ __align__(16) unsigned short Bs[2][8192];   // [buf][2][128][32]
  const int tid  = threadIdx.x;
  const int wave = tid >> 6, lane = tid & 63;
  const int quad = lane >> 4, l16 = lane & 15;
  const int wmi  = wave >> 1, wni = wave & 1;            // 4M x 2N wave grid
  const int sx   = ((l16 >> 3) & 1) << 5;

  const int tmn  = M >> 8;
  const int qq   = gridDim.x >> 3;
  const int swzb = (blockIdx.x & 7) * qq + (blockIdx.x >> 3);
  const int tm   = (swzb % tmn) << 8;
  const int tn   = (swzb / tmn) << 7;

  const int logl = (lane * 16) ^ (((lane >> 5) & 1) << 5);
  const int srow = logl >> 6;           // 0..15
  const int scol = (logl & 63) >> 1;    // 0..31
  const int NT   = K >> 6;

  auto issueA = [&](int tt, int ch) {
    glds16(&A[(size_t)(tm + (ch & 15) * 16 + srow) * K + (tt << 6) + (ch >> 4) * 32 + scol],
           (const char*)As + ((tt & 1) << 15) + ch * 1024);
  };
  auto issueB = [&](int tt, int ch) {
    glds16(&B[(size_t)(tn + (ch & 7) * 16 + srow) * K + (tt << 6) + (ch >> 3) * 32 + scol],
           (const char*)Bs + ((tt & 1) << 14) + ch * 1024);
  };

  f32x4 acc[4][4];
#pragma unroll
  for (int i = 0; i < 4; ++i)
#pragma unroll
    for (int j = 0; j < 4; ++j) acc[i][j] = fzero4();

  // prologue: t0-kh0, t0-kh1, t1-kh0 (3 groups x 3 chunks/wave)
  issueB(0, wave);     issueA(0, wave);      issueA(0, 8 + wave);
  issueB(0, 8 + wave); issueA(0, 16 + wave); issueA(0, 24 + wave);
  if (NT > 1) {
    issueB(1, wave); issueA(1, wave); issueA(1, 8 + wave);
    asm volatile("s_waitcnt vmcnt(6)" ::: "memory");
  } else {
    asm volatile("s_waitcnt vmcnt(3)" ::: "memory");
  }
  __builtin_amdgcn_s_barrier();

  for (int t = 0; t < NT; ++t) {
    const char* Asc = (const char*)As + ((t & 1) << 15);
    const char* Bsc = (const char*)Bs + ((t & 1) << 14);
    const bool h1 = (t + 1 < NT), h2 = (t + 2 < NT);
    bf16x8 aq[4], bq[4];

    // ---- phase 0: kh0 ----
#pragma unroll
    for (int g = 0; g < 4; ++g)
      bq[g] = *reinterpret_cast<const bf16x8*>(
          Bsc + (((wni * 64 + g * 16 + l16) << 6) + ((quad * 16) ^ sx)));
#pragma unroll
    for (int f = 0; f < 4; ++f)
      aq[f] = *reinterpret_cast<const bf16x8*>(
          Asc + (((wmi * 64 + f * 16 + l16) << 6) + ((quad * 16) ^ sx)));
    if (h1) {  // (t+1)-kh1 -> idle buffer
      issueB(t + 1, 8 + wave); issueA(t + 1, 16 + wave); issueA(t + 1, 24 + wave);
    }
    __builtin_amdgcn_s_setprio(1);
#pragma unroll
    for (int f = 0; f < 4; ++f)
#pragma unroll
      for (int g = 0; g < 4; ++g) acc[f][g] = MFMA16(aq[f], bq[g], acc[f][g]);
    __builtin_amdgcn_s_setprio(0);
    // drain kh1(t) (issued ph0(t-1)); keep kh0(t+1)[3] + kh1(t+1)[3] = 6.
    if (h1) asm volatile("s_waitcnt vmcnt(6)" ::: "memory");
    else    asm volatile("s_waitcnt vmcnt(0)" ::: "memory");
    __builtin_amdgcn_s_barrier();

    // ---- phase 1: kh1 ----
#pragma unroll
    for (int g = 0; g < 4; ++g)
      bq[g] = *reinterpret_cast<const bf16x8*>(
          Bsc + (8192 + ((wni * 64 + g * 16 + l16) << 6) + ((quad * 16) ^ sx)));
#pragma unroll
    for (int f = 0; f < 4; ++f)
      aq[f] = *reinterpret_cast<const bf16x8*>(
          Asc + (16384 + ((wmi * 64 + f * 16 + l16) << 6) + ((quad * 16) ^ sx)));
    if (h2) {  // (t+2)-kh0 -> current buffer; reads consumed before ph0's
               // closing barrier, which precedes this issue.
      issueB(t + 2, wave); issueA(t + 2, wave); issueA(t + 2, 8 + wave);
    }
    __builtin_amdgcn_s_setprio(1);
#pragma unroll
    for (int f = 0; f < 4; ++f)
#pragma unroll
      for (int g = 0; g < 4; ++g) acc[f][g] = MFMA16(aq[f], bq[g], acc[f][g]);
    __builtin_amdgcn_s_setprio(0);
    // drain kh0(t+1) (issued ph1(t-1)); keep kh1(t+1)[3] + kh0(t+2)[3] = 6.
    if (h2)      asm volatile("s_waitcnt vmcnt(6)" ::: "memory");
    else if (h1) asm volatile("s_waitcnt vmcnt(3)" ::: "memory");
    else         asm volatile("s_waitcnt vmcnt(0)" ::: "memory");
    __builtin_amdgcn_s_barrier();
  }

  // ---- epilogue ----
#pragma unroll
  for (int fi = 0; fi < 4; ++fi)
#pragma unroll
    for (int g = 0; g < 4; ++g)
#pragma unroll
      for (int r = 0; r < 4; ++r) {
        const int row = tm + wmi * 64 + fi * 16 + quad * 4 + r;
        const int col = tn + wni * 64 + g * 16 + l16;
        storeC(&C[(size_t)row * N + col], acc[fi][g][r]);
      }
}

// ---------------- K/V fragment packing (R13 layout) -------------------------
// Kp: per (bk, kt64) an 8192-elem block; tile (c,nt) holds lane-linear
//     B-fragments: elem(lane=quad*16+l16, j) = K[key=kt+l16*4+nt][c*32+quad*8+j]
// Vp: per (bk, kt32) a 4096-elem block; tile dt: elem(lane,j) =
//     V[key=kt+quad*8+j][dim=dt*16+l16]
__global__ __launch_bounds__(256) void kvpack(const unsigned short* __restrict__ QKV,
                                              unsigned short* __restrict__ Kp,
                                              unsigned short* __restrict__ Vp) {
  const int tid  = threadIdx.x;
  const int kt64 = blockIdx.x;           // 0..31
  const int bk   = blockIdx.y;           // b*4 + kvh
  const int b = bk >> 2, kvh = bk & 3;
  const int kt = kt64 * 64;
  const int bT = b * T_SEQ;
  const int dq = tid & 15;               // dim octet: dims dq*8..dq*8+7

  unsigned short* kdst = &Kp[(size_t)(bk * 32 + kt64) * 8192];
#pragma unroll
  for (int it = 0; it < 4; ++it) {
    int key = it * 16 + (tid >> 4);
    float4 v = *reinterpret_cast<const float4*>(
        &QKV[(size_t)(bT + kt + key) * QKVN + 2048 + kvh * HS + dq * 8]);
    int c = dq >> 2, quad = dq & 3, nt = key & 3, l16s = key >> 2;
    *reinterpret_cast<float4*>(
        &kdst[((size_t)((c * 4 + nt) * 64 + quad * 16 + l16s)) * 8]) = v;
  }

#pragma unroll
  for (int it = 0; it < 4; ++it) {
    int key = it * 16 + (tid >> 4);
    float4 v = *reinterpret_cast<const float4*>(
        &QKV[(size_t)(bT + kt + key) * QKVN + 2560 + kvh * HS + dq * 8]);
    const unsigned short* pv = reinterpret_cast<const unsigned short*>(&v);
    int kt32 = kt64 * 2 + (key >> 5);
    int quad = (key & 31) >> 3, j = key & 7;
    unsigned short* vdst = &Vp[(size_t)(bk * 64 + kt32) * 4096];
#pragma unroll
    for (int j2 = 0; j2 < 8; ++j2) {
      int d = dq * 8 + j2, dt = d >> 4, l16v = d & 15;
      vdst[((size_t)(dt * 64 + quad * 16 + l16v)) * 8 + j] = pv[j2];
    }
  }
}

// ---------------- flash attention, double-buffered async-LDS K/V (R13) ------
// grid 512 = 64 q-tiles x 8 (b,kvh); bk = blockIdx.x & 7 so all q-tiles of a
// KV group land on one XCD (round-robin dispatch) -> K/V L2-resident.
// block 256 = 4 waves = 4 heads of the group, same 32 queries. Per chunk:
// issue next chunk's 8 glds16 into the idle buffer, counted vmcnt(8) for the
// current buffer, raw barriers (no vmcnt(0) drain mid-loop).
// P tile: per-wave [32 rows][64 elems] linear, XOR swizzle byte^=(row&7)<<4
// on both the uint2 write and b128 read (alignment preserved, bits 4-6).
__global__ __launch_bounds__(256) void attn_kernel(const unsigned short* __restrict__ QKV,
                                                   const unsigned short* __restrict__ Kp,
                                                   const unsigned short* __restrict__ Vp,
                                                   unsigned short* __restrict__ Y) {
  __shared__ __align__(16) unsigned short Ks[2][8192];
  __shared__ __align__(16) unsigned short Vs[2][8192];
  __shared__ __align__(16) unsigned short Ps[4 * 2048];   // [wave][32][64]

  const int tid  = threadIdx.x;
  const int wave = tid >> 6, lane = tid & 63;
  const int quad = lane >> 4, l16 = lane & 15;
  const int bk   = blockIdx.x & 7;                        // XCD-resident group
  const int seq  = blockIdx.x >> 3;                       // 0..63
  const int qt0  = (63 - seq) * 32;                       // long blocks first
  const int kvh  = bk & 3, b = bk >> 2;
  const int h    = kvh * 4 + wave;
  const int bT   = b * T_SEQ;
  char* Pw = (char*)&Ps[wave * 2048];

  // Q fragments (A-operand: m=l16, k=quad*8+j); Q pre-scaled by log2e/sqrt(HS)
  bf16x8 qa[2][4];
#pragma unroll
  for (int mt = 0; mt < 2; ++mt)
#pragma unroll
    for (int c = 0; c < 4; ++c)
      qa[mt][c] = *reinterpret_cast<const bf16x8*>(
          &QKV[(size_t)(bT + qt0 + mt * 16 + l16) * QKVN + h * HS + c * 32 + quad * 8]);

  bf16x8 ones;
#pragma unroll
  for (int j = 0; j < 8; ++j) ones[j] = us2b(0x3F80);  // bf16 1.0

  f32x4 o[2][9];   // [mt][dt]; dt=8 accumulates row-sum l
#pragma unroll
  for (int mt = 0; mt < 2; ++mt)
#pragma unroll
    for (int dt = 0; dt < 9; ++dt) o[mt][dt] = fzero4();

  const int start = (qt0 >= 1024) ? ((qt0 - 1023) & ~63) : 0;
  const int sink  = (start > 0) ? 1 : 0;
  const int nch   = ((qt0 + 32 - start + 63) >> 6) + sink;

  // stage chunk ci into buffer buf (8 glds16/wave: 4 K parts + 4 V parts)
  auto stage = [&](int ci, int buf) {
    const int kt = (sink && ci == 0) ? 0 : start + (ci - sink) * 64;
    const unsigned short* kg = &Kp[(size_t)(bk * 32 + (kt >> 6)) * 8192 + lane * 8];
    const unsigned short* vg = &Vp[(size_t)(bk * 64 + (kt >> 5)) * 4096 + lane * 8];
#pragma unroll
    for (int i = 0; i < 4; ++i) {
      int part = wave * 4 + i;                    // wave-uniform
      glds16(kg + part * 512, &Ks[buf][part * 512]);
      glds16(vg + part * 512, &Vs[buf][part * 512]);
    }
  };

  stage(0, 0);

  for (int ci = 0; ci < nch; ++ci) {
    const int  buf = ci & 1;
    const bool is_sink = (sink && ci == 0);
    const int  kt  = is_sink ? 0 : start + (ci - sink) * 64;
    const int  rem = qt0 + 32 - kt;
    const int  kcmax = is_sink ? 1 : (rem >= 64 ? 2 : ((rem + 31) >> 5));
    const bool full  = !is_sink && (kt + 63 <= qt0) && (kt >= qt0 - 992);

    if (ci + 1 < nch) {
      stage(ci + 1, buf ^ 1);     // idle buffer; its readers finished >=1
                                  // barrier ago (end of iteration ci-1)
      asm volatile("s_waitcnt vmcnt(8)" ::: "memory");   // cur chunk landed
    } else {
      asm volatile("s_waitcnt vmcnt(0)" ::: "memory");
    }
    __builtin_amdgcn_s_barrier();

    // ---- S = Q K^T from LDS (conflict-free b128 reads) ----
    f32x4 s[2][4];
#pragma unroll
    for (int nt = 0; nt < 4; ++nt) { s[0][nt] = fzero4(); s[1][nt] = fzero4(); }
    __builtin_amdgcn_s_setprio(1);
#pragma unroll
    for (int c = 0; c < 4; ++c) {
#pragma unroll
      for (int nt = 0; nt < 4; ++nt) {
        bf16x8 kf = *reinterpret_cast<const bf16x8*>(&Ks[buf][(c * 4 + nt) * 512 + lane * 8]);
        s[0][nt] = MFMA16(qa[0][c], kf, s[0][nt]);
        s[1][nt] = MFMA16(qa[1][c], kf, s[1][nt]);
      }
    }
    __builtin_amdgcn_s_setprio(0);

    // ---- P = exp2(S) with mask (key of col: kt + l16*4 + nt) ----
    // write: elems [l16*4 .. l16*4+3] of row -> byte (row*128+l16*8)^((row&7)<<4)
    if (full) {
#pragma unroll
      for (int mt = 0; mt < 2; ++mt)
#pragma unroll
        for (int r = 0; r < 4; ++r) {
          const int row = mt * 16 + quad * 4 + r;
          uint2 pk;
          pk.x = pkhi(EXP2(s[mt][0][r]), EXP2(s[mt][1][r]));
          pk.y = pkhi(EXP2(s[mt][2][r]), EXP2(s[mt][3][r]));
          *reinterpret_cast<uint2*>(
              Pw + ((row * 128 + l16 * 8) ^ ((row & 7) << 4))) = pk;
        }
    } else {
#pragma unroll
      for (int mt = 0; mt < 2; ++mt)
#pragma unroll
        for (int r = 0; r < 4; ++r) {
          const int row = mt * 16 + quad * 4 + r;
          const int qi  = qt0 + row;
          float p[4];
#pragma unroll
          for (int nt = 0; nt < 4; ++nt) {
            int kj = kt + l16 * 4 + nt;
            bool ok = ((kj <= qi) && (kj + (WIN - 1) >= qi)) ||
                      ((kj < SINKN) && (qi >= SINKN));
            p[nt] = ok ? EXP2(s[mt][nt][r]) : 0.f;
          }
          uint2 pk;
          pk.x = pkhi(p[0], p[1]);
          pk.y = pkhi(p[2], p[3]);
          *reinterpret_cast<uint2*>(
              Pw + ((row * 128 + l16 * 8) ^ ((row & 7) << 4))) = pk;
        }
    }
    asm volatile("s_waitcnt lgkmcnt(0)" ::: "memory");  // wave-local P drain

    // ---- O += P V (+ ones column for l), V from LDS ----
    __builtin_amdgcn_s_setprio(1);
#pragma unroll
    for (int kc = 0; kc < 2; ++kc)
      if (kc < kcmax) {
#pragma unroll
        for (int mt = 0; mt < 2; ++mt) {
          const int prow = mt * 16 + l16;
          bf16x8 pf = *reinterpret_cast<const bf16x8*>(
              Pw + ((prow * 128 + kc * 64 + quad * 16) ^ ((prow & 7) << 4)));
#pragma unroll
          for (int dt = 0; dt < 8; ++dt) {
            bf16x8 vf = *reinterpret_cast<const bf16x8*>(
                &Vs[buf][kc * 4096 + dt * 512 + lane * 8]);
            o[mt][dt] = MFMA16(pf, vf, o[mt][dt]);
          }
          o[mt][8] = MFMA16(pf, ones, o[mt][8]);
        }
      }
    __builtin_amdgcn_s_setprio(0);
    asm volatile("" ::: "memory");
    __builtin_amdgcn_s_barrier();   // all reads of buf done -> restage-safe
  }

  // ---- normalize, stage in LDS (reuse Ks), coalesced Y store ----
  __syncthreads();                       // full drain before buffer reuse
  unsigned short* Yst = &Ks[0][0];       // 32 rows x 512 cols (32KB)
#pragma unroll
  for (int mt = 0; mt < 2; ++mt) {
    float inv[4];
#pragma unroll
    for (int r = 0; r < 4; ++r) inv[r] = __builtin_amdgcn_rcpf(o[mt][8][r]);
#pragma unroll
    for (int dt = 0; dt < 8; ++dt)
#pragma unroll
      for (int r = 0; r < 4; ++r)
        Yst[(mt * 16 + quad * 4 + r) * 512 + wave * 128 + dt * 16 + l16] =
            f2bu(o[mt][dt][r] * inv[r]);
  }
  __syncthreads();
#pragma unroll
  for (int it = 0; it < 8; ++it) {
    int idx = it * 256 + tid;
    int row = idx >> 6, col = (idx & 63) * 8;
    *reinterpret_cast<uint4*>(
        &Y[(size_t)(bT + qt0 + row) * CDIM + kvh * 512 + col]) =
        *reinterpret_cast<const uint4*>(&Yst[row * 512 + col]);
  }
}

// ---------------------------------------------------------------------------
extern "C" void kernel_launch(void* const* d_in, const int* in_sizes, int n_in,
                              void* d_out, int out_size, void* d_ws, size_t ws_size,
                              hipStream_t stream) {
  const float* x  = (const float*)d_in[0];
  const float* Wq = (const float*)d_in[1];
  const float* Wk = (const float*)d_in[2];
  const float* Wv = (const float*)d_in[3];
  const float* Wo = (const float*)d_in[4];
  float* out = (float*)d_out;

  // workspace layout (bf16 elems); total 62.9 MB
  unsigned short* base = (unsigned short*)d_ws;
  unsigned short* xb   = base;              // x bf16 (8388608); later Y
  unsigned short* wqb  = xb + OFF_WQ;       // Wq bf16; later Kp+Vp
  unsigned short* wob  = xb + OFF_WO;       // Wo bf16
  unsigned short* QKVb = xb + SZ_ALL;       // QKV (4096 x 3072)
  unsigned short* Kpb  = wqb;               // packed K (2097152)
  unsigned short* Vpb  = wqb + 2097152;     // packed V (2097152)
  unsigned short* Yb   = xb;                // attn out (4096 x 2048)

  // 1/sqrt(HS) * log2(e) folded into Wq so exp2 is native
  const float qscale = 0.08838834764831845f * 1.4426950408889634f;
  f2b_all<<<SZ_ALL / 1024, 256, 0, stream>>>(x, Wq, Wk, Wv, Wo, xb, qscale);

  // fused QKV projection: 256x192 tiles -> 16x16 = 256 blocks (full GPU)
  gemm_bn192<unsigned short><<<256, 512, 0, stream>>>(xb, wqb, QKVb, 4096, QKVN, 2048);

  kvpack<<<dim3(32, 8), 256, 0, stream>>>(QKVb, Kpb, Vpb);

  // attention: 1D grid, bk = id&7 -> per-XCD K/V residency (R13 config)
  attn_kernel<<<512, 256, 0, stream>>>(QKVb, Kpb, Vpb, Yb);

  // output projection: 256x128 tiles -> 16x16 = 256 blocks (R13 config)
  gemm_bn128<float><<<256, 512, 0, stream>>>(Yb, wob, out, 4096, 2048, 2048);
}